// Round 5
// baseline (195.545 us; speedup 1.0000x reference)
//
#include <hip/hip_runtime.h>
#include <math.h>

#define BB 8
#define CC 512
#define LL 1024
#define GG 32
#define CPG 16
#define NH 8
#define CH 64

typedef unsigned short ushort_t;
typedef __attribute__((ext_vector_type(8))) short short8;
typedef __attribute__((ext_vector_type(4))) float f32x4;

#define SCALE_Q 0.18033688f  // 0.125 * log2(e)

__device__ inline ushort_t f2bf(float f) {
  union { float f; unsigned u; } v;
  v.f = f;
  unsigned r = v.u + 0x7FFFu + ((v.u >> 16) & 1u);
  return (ushort_t)(r >> 16);
}

// pack two f32 -> two bf16 (truncate) in one v_perm_b32
__device__ inline unsigned pack_bf2(float lo, float hi) {
  return __builtin_amdgcn_perm(__float_as_uint(hi), __float_as_uint(lo),
                               0x07060302u);
}

// XOR-swizzled LDS index: rows of 64 bf16, 8-elt groups swizzled by row.
__device__ inline int swz(int r, int k) {
  return r * 64 + ((((k >> 3) ^ (r & 7)) << 3) | (k & 7));
}

// ---------------- GroupNorm stats -> per-(b,c) scale/shift ----------------
__global__ __launch_bounds__(256) void gn_stats_kernel(
    const float* __restrict__ x, const float* __restrict__ gn_w,
    const float* __restrict__ gn_b, float* __restrict__ s_bc,
    float* __restrict__ t_bc) {
  int b = blockIdx.x / GG;
  int g = blockIdx.x % GG;
  const float* xg = x + ((size_t)b * CC + (size_t)g * CPG) * LL;
  float sum = 0.f, sq = 0.f;
  for (int i = threadIdx.x; i < CPG * LL; i += 256) {
    float v = xg[i];
    sum += v;
    sq += v * v;
  }
#pragma unroll
  for (int off = 32; off > 0; off >>= 1) {
    sum += __shfl_down(sum, off);
    sq += __shfl_down(sq, off);
  }
  __shared__ float red[8];
  __shared__ float st[2];
  int wave = threadIdx.x >> 6;
  if ((threadIdx.x & 63) == 0) {
    red[wave] = sum;
    red[4 + wave] = sq;
  }
  __syncthreads();
  if (threadIdx.x == 0) {
    float s = red[0] + red[1] + red[2] + red[3];
    float q = red[4] + red[5] + red[6] + red[7];
    float mean = s * (1.f / (CPG * LL));
    float var = q * (1.f / (CPG * LL)) - mean * mean;
    st[0] = mean;
    st[1] = rsqrtf(var + 1e-5f);
  }
  __syncthreads();
  if (threadIdx.x < CPG) {
    int c = g * CPG + threadIdx.x;
    float w = gn_w[c];
    float sc = st[1] * w;
    s_bc[b * CC + c] = sc;
    t_bc[b * CC + c] = gn_b[c] - st[0] * sc;
  }
}

// ---------------- weights fp32 -> bf16 ----------------
__global__ __launch_bounds__(256) void convert_w_kernel(
    const float* __restrict__ qkv_w, const float* __restrict__ proj_w,
    ushort_t* __restrict__ wq, ushort_t* __restrict__ wp) {
  int idx = (blockIdx.x * 256 + threadIdx.x) * 4;
  const int N1 = 3 * CC * CC;
  float4 v;
  ushort_t* dst;
  if (idx < N1) {
    v = *(const float4*)(qkv_w + idx);
    dst = wq + idx;
  } else {
    int j = idx - N1;
    v = *(const float4*)(proj_w + j);
    dst = wp + j;
  }
  unsigned lo = f2bf(v.x) | ((unsigned)f2bf(v.y) << 16);
  unsigned hi = f2bf(v.z) | ((unsigned)f2bf(v.w) << 16);
  *(uint2*)dst = make_uint2(lo, hi);
}

// ---------------- GN apply + transpose -> xnT[b][l][c] bf16 ----------------
__global__ __launch_bounds__(256) void xnt_kernel(
    const float* __restrict__ x, const float* __restrict__ s_bc,
    const float* __restrict__ t_bc, ushort_t* __restrict__ xnT) {
  const int b = blockIdx.z;
  const int c0 = blockIdx.y * 64;
  const int l0 = blockIdx.x * 64;
  const int tid = threadIdx.x;
  __shared__ ushort_t Ts[64 * 72];
#pragma unroll
  for (int r4 = 0; r4 < 4; ++r4) {
    int c_local = (tid >> 4) + r4 * 16;
    int l_local = (tid & 15) * 4;
    int c = c0 + c_local;
    float sc = s_bc[b * CC + c], sh = t_bc[b * CC + c];
    float4 v = *(const float4*)(x + ((size_t)b * CC + c) * LL + l0 + l_local);
    float vv[4] = {v.x, v.y, v.z, v.w};
#pragma unroll
    for (int dl = 0; dl < 4; ++dl) {
      int l = l_local + dl;
      int cs = c_local ^ (((l >> 2) & 7) << 3);
      Ts[l * 72 + cs] = f2bf(vv[dl] * sc + sh);
    }
  }
  __syncthreads();
#pragma unroll
  for (int rep = 0; rep < 2; ++rep) {
    int gid = tid + rep * 256;
    int l = gid >> 3, seg = gid & 7;
    uint4 v = *(const uint4*)&Ts[l * 72 + ((seg * 8) ^ (((l >> 2) & 7) << 3))];
    *(uint4*)(xnT + ((size_t)b * LL + l0 + l) * CC + c0 + seg * 8) = v;
  }
}

// ---------------- QKV GEMM: bf16 MFMA 128x128 tiles ----------------
__global__ __launch_bounds__(256) void qkv_mfma_kernel(
    const ushort_t* __restrict__ wq, const ushort_t* __restrict__ xnT,
    const float* __restrict__ qkv_b, ushort_t* __restrict__ qT,
    ushort_t* __restrict__ kT, ushort_t* __restrict__ vbuf) {
  const int b = blockIdx.z;
  const int m0 = blockIdx.y * 128;
  const int n0 = blockIdx.x * 128;
  const int tid = threadIdx.x;
  const int w = tid >> 6, lane = tid & 63;
  const int col = lane & 15, quad = lane >> 4;
  const int wm = (w >> 1) * 64, wn = (w & 1) * 64;
  __shared__ ushort_t Smem[2 * 128 * 64];
  ushort_t* As = Smem;
  ushort_t* Bs = Smem + 128 * 64;
  f32x4 acc[4][4];
  f32x4 z = {0.f, 0.f, 0.f, 0.f};
#pragma unroll
  for (int i = 0; i < 4; ++i)
#pragma unroll
    for (int j = 0; j < 4; ++j) acc[i][j] = z;

  for (int k0 = 0; k0 < CC; k0 += 64) {
    __syncthreads();
#pragma unroll
    for (int rep = 0; rep < 4; ++rep) {
      int gid = tid + rep * 256;
      int r = gid >> 3, g = gid & 7;
      uint4 av = *(const uint4*)(wq + (size_t)(m0 + r) * CC + k0 + g * 8);
      *(uint4*)&As[swz(r, g * 8)] = av;
      uint4 bv =
          *(const uint4*)(xnT + ((size_t)b * LL + n0 + r) * CC + k0 + g * 8);
      *(uint4*)&Bs[swz(r, g * 8)] = bv;
    }
    __syncthreads();
#pragma unroll
    for (int kk = 0; kk < 2; ++kk) {
      short8 af[4], bf[4];
#pragma unroll
      for (int mi = 0; mi < 4; ++mi)
        af[mi] = *(const short8*)&As[swz(wm + mi * 16 + col, kk * 32 + quad * 8)];
#pragma unroll
      for (int ni = 0; ni < 4; ++ni)
        bf[ni] = *(const short8*)&Bs[swz(wn + ni * 16 + col, kk * 32 + quad * 8)];
#pragma unroll
      for (int mi = 0; mi < 4; ++mi)
#pragma unroll
        for (int ni = 0; ni < 4; ++ni)
          acc[mi][ni] = __builtin_amdgcn_mfma_f32_16x16x32_bf16(
              af[mi], bf[ni], acc[mi][ni], 0, 0, 0);
    }
  }
  __syncthreads();
  const int chunk_g = (m0 >> 6) + (w >> 1);
  const int sel = chunk_g % 3;
  ushort_t* Tile = Smem + (w >> 1) * 8192;
  if (sel < 2) {
    const float sc = (sel == 0) ? SCALE_Q : 1.f;
#pragma unroll
    for (int mi = 0; mi < 4; ++mi) {
      int mg = m0 + wm + mi * 16 + quad * 4;
      float b0 = qkv_b[mg + 0], b1 = qkv_b[mg + 1];
      float b2 = qkv_b[mg + 2], b3 = qkv_b[mg + 3];
      int ch = mi * 16 + quad * 4;
#pragma unroll
      for (int ni = 0; ni < 4; ++ni) {
        int lloc = wn + ni * 16 + col;
        float v0 = (acc[mi][ni][0] + b0) * sc;
        float v1 = (acc[mi][ni][1] + b1) * sc;
        float v2 = (acc[mi][ni][2] + b2) * sc;
        float v3 = (acc[mi][ni][3] + b3) * sc;
        int chs = ch ^ ((lloc & 7) << 3);
        *(uint2*)&Tile[lloc * 64 + chs] =
            make_uint2(pack_bf2(v0, v1), pack_bf2(v2, v3));
      }
    }
  } else {
#pragma unroll
    for (int mi = 0; mi < 4; ++mi)
#pragma unroll
      for (int r = 0; r < 4; ++r) {
        int ch = mi * 16 + quad * 4 + r;
        float bias = qkv_b[m0 + wm + ch];
#pragma unroll
        for (int ni = 0; ni < 4; ++ni) {
          int lloc = wn + ni * 16 + col;
          Tile[ch * 128 + lloc] =
              (ushort_t)(__float_as_uint(acc[mi][ni][r] + bias) >> 16);
        }
      }
  }
  __syncthreads();
#pragma unroll
  for (int ci = 0; ci < 2; ++ci) {
    int cg = (m0 >> 6) + ci;
    int head = cg / 3, sel2 = cg % 3;
    int bh = b * NH + head;
    ushort_t* T2 = Smem + ci * 8192;
    if (sel2 < 2) {
      ushort_t* dst = (sel2 == 0) ? qT : kT;
#pragma unroll
      for (int it = 0; it < 4; ++it) {
        int idx = tid + it * 256;
        int l = idx >> 3, seg = idx & 7;
        uint4 v = *(const uint4*)&T2[l * 64 + ((seg * 8) ^ ((l & 7) << 3))];
        *(uint4*)(dst + ((size_t)bh * LL + n0 + l) * CH + seg * 8) = v;
      }
    } else {
#pragma unroll
      for (int it = 0; it < 4; ++it) {
        int idx = tid + it * 256;
        int ch = idx >> 4, lseg = idx & 15;
        uint4 v = *(const uint4*)&T2[ch * 128 + lseg * 8];
        *(uint4*)(vbuf + ((size_t)bh * CH + ch) * LL + n0 + lseg * 8) = v;
      }
    }
  }
}

// ---- Flash attention: 128-t blocks, Q-in-regs, double-buffered K/V ----
__global__ __launch_bounds__(256) void attn_mfma_kernel(
    const ushort_t* __restrict__ qT, const ushort_t* __restrict__ kT,
    const ushort_t* __restrict__ vbuf, ushort_t* __restrict__ abuf) {
  // 512 blocks: each XCD (B&7) owns 8 heads x 8 t-tiles -> K/V set 2MB in L2
  const int B = blockIdx.x;
  const int bh = (B & 7) * 8 + (B >> 6);
  const int t0g = ((B >> 3) & 7) * 128;
  const int b = bh >> 3, h = bh & 7;
  const int tid = threadIdx.x;
  const int w = tid >> 6, lane = tid & 63;
  const int col = lane & 15, quad = lane >> 4;
  __shared__ ushort_t QPs[128 * 64];   // Q staging, then P (wave-private rows)
  __shared__ ushort_t Ks[2][64 * 64];  // double-buffered
  __shared__ ushort_t Vs[2][64 * 64];

  const int pr = tid >> 3, pg = tid & 7;  // staging coords (r=pr, r2=pr+32)
  const ushort_t* kbase = kT + ((size_t)bh * LL) * CH;
  const ushort_t* vbase = vbuf + ((size_t)bh * CH) * LL;

  // stage Q tile [t 128][c 64]
#pragma unroll
  for (int rep = 0; rep < 4; ++rep) {
    int gid = tid + rep * 256;
    int r = gid >> 3, g = gid & 7;
    uint4 v = *(const uint4*)(qT + ((size_t)bh * LL + t0g + r) * CH + g * 8);
    *(uint4*)&QPs[swz(r, g * 8)] = v;
  }
  // prefetch tile 0 K/V into registers
  uint4 pk[2], pv[2];
#pragma unroll
  for (int rep = 0; rep < 2; ++rep) {
    int r = pr + rep * 32;
    pk[rep] = *(const uint4*)(kbase + (size_t)r * CH + pg * 8);
    pv[rep] = *(const uint4*)(vbase + (size_t)r * LL + pg * 8);
  }
  __syncthreads();
  // Q B-fragments in registers for both t-strips
  short8 bq[2][2];
#pragma unroll
  for (int st = 0; st < 2; ++st)
#pragma unroll
    for (int kk = 0; kk < 2; ++kk)
      bq[st][kk] =
          *(const short8*)&QPs[swz(st * 64 + w * 16 + col, kk * 32 + quad * 8)];
  // write tile 0 into buffer 0
#pragma unroll
  for (int rep = 0; rep < 2; ++rep) {
    int r = pr + rep * 32;
    *(uint4*)&Ks[0][swz(r, pg * 8)] = pk[rep];
    *(uint4*)&Vs[0][swz(r, pg * 8)] = pv[rep];
  }
  __syncthreads();

  float m_s[2] = {0.f, 0.f};
  float lsum[2] = {0.f, 0.f};
  f32x4 oacc[2][4];
  f32x4 z = {0.f, 0.f, 0.f, 0.f};
#pragma unroll
  for (int st = 0; st < 2; ++st)
#pragma unroll
    for (int ci = 0; ci < 4; ++ci) oacc[st][ci] = z;

  for (int it = 0; it < 16; ++it) {
    const int cur = it & 1;
    // prefetch next tile global->regs (latency hidden under compute)
    if (it < 15) {
      int s0n = (it + 1) * 64;
#pragma unroll
      for (int rep = 0; rep < 2; ++rep) {
        int r = pr + rep * 32;
        pk[rep] = *(const uint4*)(kbase + (size_t)(s0n + r) * CH + pg * 8);
        pv[rep] = *(const uint4*)(vbase + (size_t)r * LL + s0n + pg * 8);
      }
    }
    // S^T[s][t] = K Q^T ; K-frags shared across both t-strips
    f32x4 sacc[2][4];
#pragma unroll
    for (int st = 0; st < 2; ++st)
#pragma unroll
      for (int si = 0; si < 4; ++si) sacc[st][si] = z;
#pragma unroll
    for (int kk = 0; kk < 2; ++kk)
#pragma unroll
      for (int si = 0; si < 4; ++si) {
        short8 ak =
            *(const short8*)&Ks[cur][swz(si * 16 + col, kk * 32 + quad * 8)];
#pragma unroll
        for (int st = 0; st < 2; ++st)
          sacc[st][si] = __builtin_amdgcn_mfma_f32_16x16x32_bf16(
              ak, bq[st][kk], sacc[st][si], 0, 0, 0);
      }
    if (it == 0) {  // freeze softmax shift at tile-0 max (range-safe)
#pragma unroll
      for (int st = 0; st < 2; ++st) {
        float mx = sacc[st][0][0];
#pragma unroll
        for (int si = 0; si < 4; ++si)
#pragma unroll
          for (int r = 0; r < 4; ++r) mx = fmaxf(mx, sacc[st][si][r]);
        mx = fmaxf(mx, __shfl_xor(mx, 16));
        mx = fmaxf(mx, __shfl_xor(mx, 32));
        m_s[st] = mx;
      }
    }
#pragma unroll
    for (int st = 0; st < 2; ++st)
#pragma unroll
      for (int si = 0; si < 4; ++si) {
        float p0 = __builtin_amdgcn_exp2f(sacc[st][si][0] - m_s[st]);
        float p1 = __builtin_amdgcn_exp2f(sacc[st][si][1] - m_s[st]);
        float p2 = __builtin_amdgcn_exp2f(sacc[st][si][2] - m_s[st]);
        float p3 = __builtin_amdgcn_exp2f(sacc[st][si][3] - m_s[st]);
        lsum[st] += (p0 + p1) + (p2 + p3);
        int base = swz(st * 64 + w * 16 + col, si * 16 + quad * 4);
        *(uint2*)&QPs[base] = make_uint2(pack_bf2(p0, p1), pack_bf2(p2, p3));
      }
    // O += P V^T ; V-frags shared across both t-strips
#pragma unroll
    for (int kk = 0; kk < 2; ++kk) {
      short8 ap[2];
#pragma unroll
      for (int st = 0; st < 2; ++st)
        ap[st] = *(const short8*)&QPs[swz(st * 64 + w * 16 + col,
                                          kk * 32 + quad * 8)];
#pragma unroll
      for (int ci = 0; ci < 4; ++ci) {
        short8 bv =
            *(const short8*)&Vs[cur][swz(ci * 16 + col, kk * 32 + quad * 8)];
#pragma unroll
        for (int st = 0; st < 2; ++st)
          oacc[st][ci] = __builtin_amdgcn_mfma_f32_16x16x32_bf16(
              ap[st], bv, oacc[st][ci], 0, 0, 0);
      }
    }
    // write prefetched tile into the other buffer (safe: barrier at it-1
    // guaranteed all waves finished reading buf cur^1)
    if (it < 15) {
#pragma unroll
      for (int rep = 0; rep < 2; ++rep) {
        int r = pr + rep * 32;
        *(uint4*)&Ks[cur ^ 1][swz(r, pg * 8)] = pk[rep];
        *(uint4*)&Vs[cur ^ 1][swz(r, pg * 8)] = pv[rep];
      }
    }
    __syncthreads();
  }
#pragma unroll
  for (int st = 0; st < 2; ++st) {
    float ls = lsum[st];
    ls += __shfl_xor(ls, 16);
    ls += __shfl_xor(ls, 32);
    float linv[4];
#pragma unroll
    for (int r = 0; r < 4; ++r)
      linv[r] = 1.f / __shfl(ls, (lane & 48) | (quad * 4 + r), 64);
#pragma unroll
    for (int r = 0; r < 4; ++r) {
      int l = t0g + st * 64 + w * 16 + quad * 4 + r;
#pragma unroll
      for (int ci = 0; ci < 4; ++ci) {
        int c = h * CH + ci * 16 + col;
        abuf[((size_t)b * LL + l) * CC + c] = f2bf(oacc[st][ci][r] * linv[r]);
      }
    }
  }
}

// ---------------- proj GEMM + bias + residual (64m x 128n tiles) ----------------
__global__ __launch_bounds__(256) void proj_mfma_kernel(
    const ushort_t* __restrict__ wp, const ushort_t* __restrict__ abuf,
    const float* __restrict__ proj_b, const float* __restrict__ x,
    float* __restrict__ out) {
  const int b = blockIdx.z;
  const int m0 = blockIdx.y * 64;
  const int n0 = blockIdx.x * 128;
  const int tid = threadIdx.x;
  const int w = tid >> 6, lane = tid & 63;
  const int col = lane & 15, quad = lane >> 4;
  const int wm = (w >> 1) * 32, wn = (w & 1) * 64;
  __shared__ ushort_t As[64 * 64];
  __shared__ ushort_t Bs[128 * 64];
  f32x4 acc[2][4];
  f32x4 z = {0.f, 0.f, 0.f, 0.f};
#pragma unroll
  for (int i = 0; i < 2; ++i)
#pragma unroll
    for (int j = 0; j < 4; ++j) acc[i][j] = z;

  for (int k0 = 0; k0 < CC; k0 += 64) {
    __syncthreads();
#pragma unroll
    for (int rep = 0; rep < 2; ++rep) {
      int idx = tid + rep * 256;
      int r = idx >> 3, g = idx & 7;
      uint4 av = *(const uint4*)(wp + (size_t)(m0 + r) * CC + k0 + g * 8);
      *(uint4*)&As[swz(r, g * 8)] = av;
    }
#pragma unroll
    for (int rep = 0; rep < 4; ++rep) {
      int idx = tid + rep * 256;
      int r = idx >> 3, g = idx & 7;
      uint4 bv =
          *(const uint4*)(abuf + ((size_t)b * LL + n0 + r) * CC + k0 + g * 8);
      *(uint4*)&Bs[swz(r, g * 8)] = bv;
    }
    __syncthreads();
#pragma unroll
    for (int kk = 0; kk < 2; ++kk) {
      short8 af[2], bf[4];
#pragma unroll
      for (int mi = 0; mi < 2; ++mi)
        af[mi] = *(const short8*)&As[swz(wm + mi * 16 + col, kk * 32 + quad * 8)];
#pragma unroll
      for (int ni = 0; ni < 4; ++ni)
        bf[ni] = *(const short8*)&Bs[swz(wn + ni * 16 + col, kk * 32 + quad * 8)];
#pragma unroll
      for (int mi = 0; mi < 2; ++mi)
#pragma unroll
        for (int ni = 0; ni < 4; ++ni)
          acc[mi][ni] = __builtin_amdgcn_mfma_f32_16x16x32_bf16(
              af[mi], bf[ni], acc[mi][ni], 0, 0, 0);
    }
  }
#pragma unroll
  for (int mi = 0; mi < 2; ++mi)
#pragma unroll
    for (int r = 0; r < 4; ++r) {
      int o = m0 + wm + mi * 16 + quad * 4 + r;
      float bias = proj_b[o];
#pragma unroll
      for (int ni = 0; ni < 4; ++ni) {
        int l = n0 + wn + ni * 16 + col;
        size_t off = ((size_t)b * CC + o) * LL + l;
        out[off] = x[off] + bias + acc[mi][ni][r];
      }
    }
}

extern "C" void kernel_launch(void* const* d_in, const int* in_sizes, int n_in,
                              void* d_out, int out_size, void* d_ws,
                              size_t ws_size, hipStream_t stream) {
  const float* x = (const float*)d_in[0];
  const float* gn_w = (const float*)d_in[1];
  const float* gn_b = (const float*)d_in[2];
  const float* qkv_w = (const float*)d_in[3];
  const float* qkv_b = (const float*)d_in[4];
  const float* proj_w = (const float*)d_in[5];
  const float* proj_b = (const float*)d_in[6];
  float* out = (float*)d_out;

  char* ws = (char*)d_ws;
  float* s_bc = (float*)ws;
  float* t_bc = s_bc + BB * CC;
  ushort_t* wq = (ushort_t*)(t_bc + BB * CC);
  ushort_t* wp = wq + (size_t)3 * CC * CC;
  ushort_t* xnT = wp + (size_t)CC * CC;
  ushort_t* qT = xnT + (size_t)BB * LL * CC;
  ushort_t* kT = qT + (size_t)BB * NH * LL * CH;
  ushort_t* vb = kT + (size_t)BB * NH * LL * CH;
  ushort_t* abuf = vb + (size_t)BB * NH * LL * CH;

  gn_stats_kernel<<<BB * GG, 256, 0, stream>>>(x, gn_w, gn_b, s_bc, t_bc);
  convert_w_kernel<<<1024, 256, 0, stream>>>(qkv_w, proj_w, wq, wp);
  xnt_kernel<<<dim3(LL / 64, CC / 64, BB), 256, 0, stream>>>(x, s_bc, t_bc,
                                                             xnT);
  qkv_mfma_kernel<<<dim3(LL / 128, (3 * CC) / 128, BB), 256, 0, stream>>>(
      wq, xnT, qkv_b, qT, kT, vb);
  attn_mfma_kernel<<<dim3(512), 256, 0, stream>>>(qT, kT, vb, abuf);
  proj_mfma_kernel<<<dim3(LL / 128, CC / 64, BB), 256, 0, stream>>>(
      wp, abuf, proj_b, x, out);
}

// Round 6
// 172.179 us; speedup vs baseline: 1.1357x; 1.1357x over previous
//
#include <hip/hip_runtime.h>
#include <math.h>

#define BB 8
#define CC 512
#define LL 1024
#define GG 32
#define CPG 16
#define NH 8
#define CH 64

typedef unsigned short ushort_t;
typedef __attribute__((ext_vector_type(8))) short short8;
typedef __attribute__((ext_vector_type(4))) float f32x4;

#define SCALE_Q 0.18033688f  // 0.125 * log2(e)

__device__ inline ushort_t f2bf(float f) {
  union { float f; unsigned u; } v;
  v.f = f;
  unsigned r = v.u + 0x7FFFu + ((v.u >> 16) & 1u);
  return (ushort_t)(r >> 16);
}

// pack two f32 -> two bf16 (truncate) in one v_perm_b32
__device__ inline unsigned pack_bf2(float lo, float hi) {
  return __builtin_amdgcn_perm(__float_as_uint(hi), __float_as_uint(lo),
                               0x07060302u);
}

__device__ inline float bf2f(ushort_t u) {
  union { unsigned u; float f; } v;
  v.u = ((unsigned)u) << 16;
  return v.f;
}

// XOR-swizzled LDS index: rows of 64 bf16, 8-elt groups swizzled by row.
__device__ inline int swz(int r, int k) {
  return r * 64 + ((((k >> 3) ^ (r & 7)) << 3) | (k & 7));
}

// ---------------- GroupNorm stats -> per-(b,c) scale/shift ----------------
__global__ __launch_bounds__(256) void gn_stats_kernel(
    const float* __restrict__ x, const float* __restrict__ gn_w,
    const float* __restrict__ gn_b, float* __restrict__ s_bc,
    float* __restrict__ t_bc) {
  int b = blockIdx.x / GG;
  int g = blockIdx.x % GG;
  const float* xg = x + ((size_t)b * CC + (size_t)g * CPG) * LL;
  float sum = 0.f, sq = 0.f;
  for (int i = threadIdx.x; i < CPG * LL; i += 256) {
    float v = xg[i];
    sum += v;
    sq += v * v;
  }
#pragma unroll
  for (int off = 32; off > 0; off >>= 1) {
    sum += __shfl_down(sum, off);
    sq += __shfl_down(sq, off);
  }
  __shared__ float red[8];
  __shared__ float st[2];
  int wave = threadIdx.x >> 6;
  if ((threadIdx.x & 63) == 0) {
    red[wave] = sum;
    red[4 + wave] = sq;
  }
  __syncthreads();
  if (threadIdx.x == 0) {
    float s = red[0] + red[1] + red[2] + red[3];
    float q = red[4] + red[5] + red[6] + red[7];
    float mean = s * (1.f / (CPG * LL));
    float var = q * (1.f / (CPG * LL)) - mean * mean;
    st[0] = mean;
    st[1] = rsqrtf(var + 1e-5f);
  }
  __syncthreads();
  if (threadIdx.x < CPG) {
    int c = g * CPG + threadIdx.x;
    float w = gn_w[c];
    float sc = st[1] * w;
    s_bc[b * CC + c] = sc;
    t_bc[b * CC + c] = gn_b[c] - st[0] * sc;
  }
}

// ---------------- weights fp32 -> bf16 ----------------
__global__ __launch_bounds__(256) void convert_w_kernel(
    const float* __restrict__ qkv_w, const float* __restrict__ proj_w,
    ushort_t* __restrict__ wq, ushort_t* __restrict__ wp) {
  int idx = (blockIdx.x * 256 + threadIdx.x) * 4;
  const int N1 = 3 * CC * CC;
  float4 v;
  ushort_t* dst;
  if (idx < N1) {
    v = *(const float4*)(qkv_w + idx);
    dst = wq + idx;
  } else {
    int j = idx - N1;
    v = *(const float4*)(proj_w + j);
    dst = wp + j;
  }
  unsigned lo = f2bf(v.x) | ((unsigned)f2bf(v.y) << 16);
  unsigned hi = f2bf(v.z) | ((unsigned)f2bf(v.w) << 16);
  *(uint2*)dst = make_uint2(lo, hi);
}

// ---------------- GN apply + transpose -> xnT[b][l][c] bf16 ----------------
__global__ __launch_bounds__(256) void xnt_kernel(
    const float* __restrict__ x, const float* __restrict__ s_bc,
    const float* __restrict__ t_bc, ushort_t* __restrict__ xnT) {
  const int b = blockIdx.z;
  const int c0 = blockIdx.y * 64;
  const int l0 = blockIdx.x * 64;
  const int tid = threadIdx.x;
  __shared__ ushort_t Ts[64 * 72];
#pragma unroll
  for (int r4 = 0; r4 < 4; ++r4) {
    int c_local = (tid >> 4) + r4 * 16;
    int l_local = (tid & 15) * 4;
    int c = c0 + c_local;
    float sc = s_bc[b * CC + c], sh = t_bc[b * CC + c];
    float4 v = *(const float4*)(x + ((size_t)b * CC + c) * LL + l0 + l_local);
    float vv[4] = {v.x, v.y, v.z, v.w};
#pragma unroll
    for (int dl = 0; dl < 4; ++dl) {
      int l = l_local + dl;
      int cs = c_local ^ (((l >> 2) & 7) << 3);
      Ts[l * 72 + cs] = f2bf(vv[dl] * sc + sh);
    }
  }
  __syncthreads();
#pragma unroll
  for (int rep = 0; rep < 2; ++rep) {
    int gid = tid + rep * 256;
    int l = gid >> 3, seg = gid & 7;
    uint4 v = *(const uint4*)&Ts[l * 72 + ((seg * 8) ^ (((l >> 2) & 7) << 3))];
    *(uint4*)(xnT + ((size_t)b * LL + l0 + l) * CC + c0 + seg * 8) = v;
  }
}

// ---------------- QKV GEMM: bf16 MFMA 128x128 tiles ----------------
__global__ __launch_bounds__(256) void qkv_mfma_kernel(
    const ushort_t* __restrict__ wq, const ushort_t* __restrict__ xnT,
    const float* __restrict__ qkv_b, ushort_t* __restrict__ qT,
    ushort_t* __restrict__ kT, ushort_t* __restrict__ vbuf) {
  const int b = blockIdx.z;
  const int m0 = blockIdx.y * 128;
  const int n0 = blockIdx.x * 128;
  const int tid = threadIdx.x;
  const int w = tid >> 6, lane = tid & 63;
  const int col = lane & 15, quad = lane >> 4;
  const int wm = (w >> 1) * 64, wn = (w & 1) * 64;
  __shared__ ushort_t Smem[2 * 128 * 64];
  ushort_t* As = Smem;
  ushort_t* Bs = Smem + 128 * 64;
  f32x4 acc[4][4];
  f32x4 z = {0.f, 0.f, 0.f, 0.f};
#pragma unroll
  for (int i = 0; i < 4; ++i)
#pragma unroll
    for (int j = 0; j < 4; ++j) acc[i][j] = z;

  for (int k0 = 0; k0 < CC; k0 += 64) {
    __syncthreads();
#pragma unroll
    for (int rep = 0; rep < 4; ++rep) {
      int gid = tid + rep * 256;
      int r = gid >> 3, g = gid & 7;
      uint4 av = *(const uint4*)(wq + (size_t)(m0 + r) * CC + k0 + g * 8);
      *(uint4*)&As[swz(r, g * 8)] = av;
      uint4 bv =
          *(const uint4*)(xnT + ((size_t)b * LL + n0 + r) * CC + k0 + g * 8);
      *(uint4*)&Bs[swz(r, g * 8)] = bv;
    }
    __syncthreads();
#pragma unroll
    for (int kk = 0; kk < 2; ++kk) {
      short8 af[4], bf[4];
#pragma unroll
      for (int mi = 0; mi < 4; ++mi)
        af[mi] = *(const short8*)&As[swz(wm + mi * 16 + col, kk * 32 + quad * 8)];
#pragma unroll
      for (int ni = 0; ni < 4; ++ni)
        bf[ni] = *(const short8*)&Bs[swz(wn + ni * 16 + col, kk * 32 + quad * 8)];
#pragma unroll
      for (int mi = 0; mi < 4; ++mi)
#pragma unroll
        for (int ni = 0; ni < 4; ++ni)
          acc[mi][ni] = __builtin_amdgcn_mfma_f32_16x16x32_bf16(
              af[mi], bf[ni], acc[mi][ni], 0, 0, 0);
    }
  }
  __syncthreads();
  const int chunk_g = (m0 >> 6) + (w >> 1);
  const int sel = chunk_g % 3;
  ushort_t* Tile = Smem + (w >> 1) * 8192;
  if (sel < 2) {
    const float sc = (sel == 0) ? SCALE_Q : 1.f;
#pragma unroll
    for (int mi = 0; mi < 4; ++mi) {
      int mg = m0 + wm + mi * 16 + quad * 4;
      float b0 = qkv_b[mg + 0], b1 = qkv_b[mg + 1];
      float b2 = qkv_b[mg + 2], b3 = qkv_b[mg + 3];
      int ch = mi * 16 + quad * 4;
#pragma unroll
      for (int ni = 0; ni < 4; ++ni) {
        int lloc = wn + ni * 16 + col;
        float v0 = (acc[mi][ni][0] + b0) * sc;
        float v1 = (acc[mi][ni][1] + b1) * sc;
        float v2 = (acc[mi][ni][2] + b2) * sc;
        float v3 = (acc[mi][ni][3] + b3) * sc;
        int chs = ch ^ ((lloc & 7) << 3);
        *(uint2*)&Tile[lloc * 64 + chs] =
            make_uint2(pack_bf2(v0, v1), pack_bf2(v2, v3));
      }
    }
  } else {
#pragma unroll
    for (int mi = 0; mi < 4; ++mi)
#pragma unroll
      for (int r = 0; r < 4; ++r) {
        int ch = mi * 16 + quad * 4 + r;
        float bias = qkv_b[m0 + wm + ch];
#pragma unroll
        for (int ni = 0; ni < 4; ++ni) {
          int lloc = wn + ni * 16 + col;
          Tile[ch * 128 + lloc] =
              (ushort_t)(__float_as_uint(acc[mi][ni][r] + bias) >> 16);
        }
      }
  }
  __syncthreads();
#pragma unroll
  for (int ci = 0; ci < 2; ++ci) {
    int cg = (m0 >> 6) + ci;
    int head = cg / 3, sel2 = cg % 3;
    int bh = b * NH + head;
    ushort_t* T2 = Smem + ci * 8192;
    if (sel2 < 2) {
      ushort_t* dst = (sel2 == 0) ? qT : kT;
#pragma unroll
      for (int it = 0; it < 4; ++it) {
        int idx = tid + it * 256;
        int l = idx >> 3, seg = idx & 7;
        uint4 v = *(const uint4*)&T2[l * 64 + ((seg * 8) ^ ((l & 7) << 3))];
        *(uint4*)(dst + ((size_t)bh * LL + n0 + l) * CH + seg * 8) = v;
      }
    } else {
#pragma unroll
      for (int it = 0; it < 4; ++it) {
        int idx = tid + it * 256;
        int ch = idx >> 4, lseg = idx & 15;
        uint4 v = *(const uint4*)&T2[ch * 128 + lseg * 8];
        *(uint4*)(vbuf + ((size_t)bh * CH + ch) * LL + n0 + lseg * 8) = v;
      }
    }
  }
}

// ---- Flash attention: split-s (2 halves), 128-t blocks, 2-strip sharing ----
// partials: partO[ph][bh][l][ch] bf16 (normalized O), lml/lmm[ph][bh*LL+l] f32
__global__ __launch_bounds__(256) void attn_mfma_kernel(
    const ushort_t* __restrict__ qT, const ushort_t* __restrict__ kT,
    const ushort_t* __restrict__ vbuf, ushort_t* __restrict__ partO,
    float* __restrict__ lml, float* __restrict__ lmm) {
  // 1024 blocks; XCD (B&7) owns bh in [xcd*8, xcd*8+8) -> K/V 2MB in its L2
  const int B = blockIdx.x;
  const int j = B >> 3;
  const int bh = (B & 7) * 8 + (j & 7);
  const int tt = (j >> 3) & 7;
  const int sh = j >> 6;  // s-half
  const int t0g = tt * 128;
  const int s_base = sh * 512;
  const int tid = threadIdx.x;
  const int w = tid >> 6, lane = tid & 63;
  const int col = lane & 15, quad = lane >> 4;
  const int strip = w * 16;
  __shared__ ushort_t QPs[128 * 64];  // Q staging, then P (wave-private rows)
  __shared__ ushort_t Ks[64 * 64];
  __shared__ ushort_t Vs[64 * 64];

  // stage Q tile [t 128][c 64]
#pragma unroll
  for (int rep = 0; rep < 4; ++rep) {
    int gid = tid + rep * 256;
    int r = gid >> 3, g = gid & 7;
    uint4 v = *(const uint4*)(qT + ((size_t)bh * LL + t0g + r) * CH + g * 8);
    *(uint4*)&QPs[swz(r, g * 8)] = v;
  }
  __syncthreads();
  // Q B-fragments in registers for both t-strips
  short8 bq[2][2];
#pragma unroll
  for (int st = 0; st < 2; ++st)
#pragma unroll
    for (int kk = 0; kk < 2; ++kk)
      bq[st][kk] =
          *(const short8*)&QPs[swz(st * 64 + strip + col, kk * 32 + quad * 8)];

  float m_s[2] = {0.f, 0.f};
  float lsum[2] = {0.f, 0.f};
  f32x4 oacc[2][4];
  f32x4 z = {0.f, 0.f, 0.f, 0.f};
#pragma unroll
  for (int st = 0; st < 2; ++st)
#pragma unroll
    for (int ci = 0; ci < 4; ++ci) oacc[st][ci] = z;

  for (int it = 0; it < 8; ++it) {
    const int s0 = s_base + it * 64;
    __syncthreads();
#pragma unroll
    for (int rep = 0; rep < 2; ++rep) {
      int gid = tid + rep * 256;
      int r = gid >> 3, g = gid & 7;
      uint4 kv = *(const uint4*)(kT + ((size_t)bh * LL + s0 + r) * CH + g * 8);
      *(uint4*)&Ks[swz(r, g * 8)] = kv;
      uint4 vv = *(const uint4*)(vbuf + ((size_t)bh * CH + r) * LL + s0 + g * 8);
      *(uint4*)&Vs[swz(r, g * 8)] = vv;
    }
    __syncthreads();
    // S^T[s][t] = K Q^T ; K-frags shared across both t-strips
    f32x4 sacc[2][4];
#pragma unroll
    for (int st = 0; st < 2; ++st)
#pragma unroll
      for (int si = 0; si < 4; ++si) sacc[st][si] = z;
#pragma unroll
    for (int kk = 0; kk < 2; ++kk)
#pragma unroll
      for (int si = 0; si < 4; ++si) {
        short8 ak = *(const short8*)&Ks[swz(si * 16 + col, kk * 32 + quad * 8)];
#pragma unroll
        for (int st = 0; st < 2; ++st)
          sacc[st][si] = __builtin_amdgcn_mfma_f32_16x16x32_bf16(
              ak, bq[st][kk], sacc[st][si], 0, 0, 0);
      }
    if (it == 0) {  // freeze per-half softmax shift at this half's first tile
#pragma unroll
      for (int st = 0; st < 2; ++st) {
        float mx = sacc[st][0][0];
#pragma unroll
        for (int si = 0; si < 4; ++si)
#pragma unroll
          for (int r = 0; r < 4; ++r) mx = fmaxf(mx, sacc[st][si][r]);
        mx = fmaxf(mx, __shfl_xor(mx, 16));
        mx = fmaxf(mx, __shfl_xor(mx, 32));
        m_s[st] = mx;
      }
    }
#pragma unroll
    for (int st = 0; st < 2; ++st)
#pragma unroll
      for (int si = 0; si < 4; ++si) {
        float p0 = __builtin_amdgcn_exp2f(sacc[st][si][0] - m_s[st]);
        float p1 = __builtin_amdgcn_exp2f(sacc[st][si][1] - m_s[st]);
        float p2 = __builtin_amdgcn_exp2f(sacc[st][si][2] - m_s[st]);
        float p3 = __builtin_amdgcn_exp2f(sacc[st][si][3] - m_s[st]);
        lsum[st] += (p0 + p1) + (p2 + p3);
        int base = swz(st * 64 + strip + col, si * 16 + quad * 4);
        *(uint2*)&QPs[base] = make_uint2(pack_bf2(p0, p1), pack_bf2(p2, p3));
      }
    // O += P V^T ; V-frags shared across both t-strips
#pragma unroll
    for (int kk = 0; kk < 2; ++kk) {
      short8 ap[2];
#pragma unroll
      for (int st = 0; st < 2; ++st)
        ap[st] = *(const short8*)&QPs[swz(st * 64 + strip + col,
                                          kk * 32 + quad * 8)];
#pragma unroll
      for (int ci = 0; ci < 4; ++ci) {
        short8 bv = *(const short8*)&Vs[swz(ci * 16 + col, kk * 32 + quad * 8)];
#pragma unroll
        for (int st = 0; st < 2; ++st)
          oacc[st][ci] = __builtin_amdgcn_mfma_f32_16x16x32_bf16(
              ap[st], bv, oacc[st][ci], 0, 0, 0);
      }
    }
  }
  // finalize: full row-sum l (lane t = strip+col), write partials
  ushort_t* pO = partO + (size_t)sh * (64 * LL * CH);
  float* pl = lml + (size_t)sh * (64 * LL);
  float* pm = lmm + (size_t)sh * (64 * LL);
#pragma unroll
  for (int st = 0; st < 2; ++st) {
    float ls = lsum[st];
    ls += __shfl_xor(ls, 16);
    ls += __shfl_xor(ls, 32);
    if (lane < 16) {  // quad 0 lanes own t = strip+col
      int t = t0g + st * 64 + strip + col;
      pl[(size_t)bh * LL + t] = ls;
      pm[(size_t)bh * LL + t] = m_s[st];
    }
    float linv[4];
#pragma unroll
    for (int r = 0; r < 4; ++r)
      linv[r] = 1.f / __shfl(ls, (lane & 48) | (quad * 4 + r), 64);
#pragma unroll
    for (int r = 0; r < 4; ++r) {
      int t = t0g + st * 64 + strip + quad * 4 + r;
#pragma unroll
      for (int ci = 0; ci < 4; ++ci) {
        int c = ci * 16 + col;
        pO[((size_t)bh * LL + t) * CH + c] = f2bf(oacc[st][ci][r] * linv[r]);
      }
    }
  }
}

// ---- combine the two s-halves: O = (w1*O1n + w2*O2n)/(w1+w2) ----
__global__ __launch_bounds__(256) void attn_combine_kernel(
    const ushort_t* __restrict__ partO, const float* __restrict__ lml,
    const float* __restrict__ lmm, ushort_t* __restrict__ abuf) {
  const int gid = blockIdx.x * 256 + threadIdx.x;
  const int row = gid >> 3, seg = gid & 7;  // row = bh*LL + l
  const float l1 = lml[row], m1 = lmm[row];
  const float l2 = lml[64 * LL + row], m2 = lmm[64 * LL + row];
  const float M = fmaxf(m1, m2);
  float w1 = l1 * __builtin_amdgcn_exp2f(m1 - M);
  float w2 = l2 * __builtin_amdgcn_exp2f(m2 - M);
  const float inv = 1.f / (w1 + w2);
  w1 *= inv;
  w2 *= inv;
  const ushort_t* p1 = partO + (size_t)row * CH + seg * 8;
  const ushort_t* p2 = p1 + (size_t)64 * LL * CH;
  uint4 a = *(const uint4*)p1;
  uint4 b4 = *(const uint4*)p2;
  const ushort_t* ua = (const ushort_t*)&a;
  const ushort_t* ub = (const ushort_t*)&b4;
  float o[8];
#pragma unroll
  for (int i = 0; i < 8; ++i) o[i] = w1 * bf2f(ua[i]) + w2 * bf2f(ub[i]);
  uint4 res;
  res.x = pack_bf2(o[0], o[1]);
  res.y = pack_bf2(o[2], o[3]);
  res.z = pack_bf2(o[4], o[5]);
  res.w = pack_bf2(o[6], o[7]);
  const int bh = row >> 10, l = row & (LL - 1);
  const int b = bh >> 3, h = bh & 7;
  *(uint4*)(abuf + ((size_t)b * LL + l) * CC + h * CH + seg * 8) = res;
}

// ---------------- proj GEMM + bias + residual (64m x 128n tiles) ----------------
__global__ __launch_bounds__(256) void proj_mfma_kernel(
    const ushort_t* __restrict__ wp, const ushort_t* __restrict__ abuf,
    const float* __restrict__ proj_b, const float* __restrict__ x,
    float* __restrict__ out) {
  const int b = blockIdx.z;
  const int m0 = blockIdx.y * 64;
  const int n0 = blockIdx.x * 128;
  const int tid = threadIdx.x;
  const int w = tid >> 6, lane = tid & 63;
  const int col = lane & 15, quad = lane >> 4;
  const int wm = (w >> 1) * 32, wn = (w & 1) * 64;
  __shared__ ushort_t As[64 * 64];
  __shared__ ushort_t Bs[128 * 64];
  f32x4 acc[2][4];
  f32x4 z = {0.f, 0.f, 0.f, 0.f};
#pragma unroll
  for (int i = 0; i < 2; ++i)
#pragma unroll
    for (int j = 0; j < 4; ++j) acc[i][j] = z;

  for (int k0 = 0; k0 < CC; k0 += 64) {
    __syncthreads();
#pragma unroll
    for (int rep = 0; rep < 2; ++rep) {
      int idx = tid + rep * 256;
      int r = idx >> 3, g = idx & 7;
      uint4 av = *(const uint4*)(wp + (size_t)(m0 + r) * CC + k0 + g * 8);
      *(uint4*)&As[swz(r, g * 8)] = av;
    }
#pragma unroll
    for (int rep = 0; rep < 4; ++rep) {
      int idx = tid + rep * 256;
      int r = idx >> 3, g = idx & 7;
      uint4 bv =
          *(const uint4*)(abuf + ((size_t)b * LL + n0 + r) * CC + k0 + g * 8);
      *(uint4*)&Bs[swz(r, g * 8)] = bv;
    }
    __syncthreads();
#pragma unroll
    for (int kk = 0; kk < 2; ++kk) {
      short8 af[2], bf[4];
#pragma unroll
      for (int mi = 0; mi < 2; ++mi)
        af[mi] = *(const short8*)&As[swz(wm + mi * 16 + col, kk * 32 + quad * 8)];
#pragma unroll
      for (int ni = 0; ni < 4; ++ni)
        bf[ni] = *(const short8*)&Bs[swz(wn + ni * 16 + col, kk * 32 + quad * 8)];
#pragma unroll
      for (int mi = 0; mi < 2; ++mi)
#pragma unroll
        for (int ni = 0; ni < 4; ++ni)
          acc[mi][ni] = __builtin_amdgcn_mfma_f32_16x16x32_bf16(
              af[mi], bf[ni], acc[mi][ni], 0, 0, 0);
    }
  }
#pragma unroll
  for (int mi = 0; mi < 2; ++mi)
#pragma unroll
    for (int r = 0; r < 4; ++r) {
      int o = m0 + wm + mi * 16 + quad * 4 + r;
      float bias = proj_b[o];
#pragma unroll
      for (int ni = 0; ni < 4; ++ni) {
        int l = n0 + wn + ni * 16 + col;
        size_t off = ((size_t)b * CC + o) * LL + l;
        out[off] = x[off] + bias + acc[mi][ni][r];
      }
    }
}

extern "C" void kernel_launch(void* const* d_in, const int* in_sizes, int n_in,
                              void* d_out, int out_size, void* d_ws,
                              size_t ws_size, hipStream_t stream) {
  const float* x = (const float*)d_in[0];
  const float* gn_w = (const float*)d_in[1];
  const float* gn_b = (const float*)d_in[2];
  const float* qkv_w = (const float*)d_in[3];
  const float* qkv_b = (const float*)d_in[4];
  const float* proj_w = (const float*)d_in[5];
  const float* proj_b = (const float*)d_in[6];
  float* out = (float*)d_out;

  char* ws = (char*)d_ws;
  float* s_bc = (float*)ws;
  float* t_bc = s_bc + BB * CC;
  ushort_t* wq = (ushort_t*)(t_bc + BB * CC);
  ushort_t* wp = wq + (size_t)3 * CC * CC;
  ushort_t* xnT = wp + (size_t)CC * CC;
  ushort_t* qT = xnT + (size_t)BB * LL * CC;
  ushort_t* kT = qT + (size_t)BB * NH * LL * CH;
  ushort_t* vb = kT + (size_t)BB * NH * LL * CH;
  ushort_t* abuf = vb + (size_t)BB * NH * LL * CH;
  ushort_t* partO = abuf + (size_t)BB * LL * CC;            // 2*64*LL*CH bf16
  float* lml = (float*)(partO + (size_t)2 * 64 * LL * CH);  // 2*64*LL f32
  float* lmm = lml + (size_t)2 * 64 * LL;

  gn_stats_kernel<<<BB * GG, 256, 0, stream>>>(x, gn_w, gn_b, s_bc, t_bc);
  convert_w_kernel<<<1024, 256, 0, stream>>>(qkv_w, proj_w, wq, wp);
  xnt_kernel<<<dim3(LL / 64, CC / 64, BB), 256, 0, stream>>>(x, s_bc, t_bc,
                                                             xnT);
  qkv_mfma_kernel<<<dim3(LL / 128, (3 * CC) / 128, BB), 256, 0, stream>>>(
      wq, xnT, qkv_b, qT, kT, vb);
  attn_mfma_kernel<<<dim3(1024), 256, 0, stream>>>(qT, kT, vb, partO, lml,
                                                   lmm);
  attn_combine_kernel<<<dim3(2048), 256, 0, stream>>>(partO, lml, lmm, abuf);
  proj_mfma_kernel<<<dim3(LL / 128, CC / 64, BB), 256, 0, stream>>>(
      wp, abuf, proj_b, x, out);
}